// Round 4
// baseline (1773.775 us; speedup 1.0000x reference)
//
#include <hip/hip_runtime.h>
#include <hip/hip_bf16.h>
#include <math.h>

// LatentGraphLearner: attn = softmax(top20-mask(h Wq^T Wk h^T / sqrt(D) + ps*prior, diag=-inf))
// N=8192, D=512, TOPK=20, fp32 in/out.
//
// Correctness strategy: REPLICATE the fp32 reference arithmetic bit-for-bit.
// CPU BLAS (OpenBLAS / XLA-Eigen) sgemm microkernels use one accumulator per C
// element with k-sequential fp32 FMA -> Q32/K32 here are computed as k-ascending
// fmaf chains and stored fp32 (matching np's Q,K exactly under that model).
// Bulk logits via bf16 MFMA are ONLY a candidate pre-filter (noise ~3.3e-3;
// margin 0.20 = 60 sigma). Every extracted candidate is re-scored with the
// replicated fp32 chain: fmaf over k ascending, then fdiv_rn by f32(sqrt(512)),
// then fadd_rn(fmul_rn(ps, prior)) -- np's exact op sequence, no contraction.
// Top-20 ranked by (fp32 value DESC, index ASC) = lax.top_k semantics.

#define MARGIN 0.20f
#define RSQRT_D 0.04419417382415922f

typedef __attribute__((ext_vector_type(8))) short short8;
typedef __attribute__((ext_vector_type(4))) float f32x4;

__device__ __forceinline__ unsigned long long ordkey(float v, int j) {
  unsigned u = __float_as_uint(v);
  u = (u & 0x80000000u) ? ~u : (u | 0x80000000u);
  return ((unsigned long long)u << 32) | (unsigned)(8191 - j);
}
__device__ __forceinline__ float keyval(unsigned long long k) {
  unsigned u = (unsigned)(k >> 32);
  u = (u & 0x80000000u) ? (u ^ 0x80000000u) : ~u;
  return __uint_as_float(u);
}
__device__ __forceinline__ int keyidx(unsigned long long k) {
  return 8191 - (int)(k & 0xFFFFFFFFull);
}

// ---- K1: Q = h @ Wq^T, K = h @ Wk^T; fp32 k-sequential fmaf chains (BLAS-replicating),
//          fp32 + bf16 outputs ----
__global__ __launch_bounds__(256) void k1_qk(const float* __restrict__ h,
                                             const float* __restrict__ Wq,
                                             const float* __restrict__ Wk,
                                             float* __restrict__ Q32,
                                             float* __restrict__ K32,
                                             __hip_bfloat16* __restrict__ Qb,
                                             __hip_bfloat16* __restrict__ Kb) {
  __shared__ float hs[64][17];
  __shared__ float wqs[64][17];
  __shared__ float wks[64][17];
  const int t = threadIdx.x;
  const int tx = t & 15, ty = t >> 4;
  const int i0 = blockIdx.y * 64, e0 = blockIdx.x * 64;
  const int r = t >> 2, c4 = (t & 3) * 4;
  float aq[4][4] = {};
  float ak[4][4] = {};
  for (int k0 = 0; k0 < 512; k0 += 16) {   // k strictly ascending
    __syncthreads();
    {
      const float4 hv = *(const float4*)&h[(size_t)(i0 + r) * 512 + k0 + c4];
      hs[r][c4 + 0] = hv.x; hs[r][c4 + 1] = hv.y; hs[r][c4 + 2] = hv.z; hs[r][c4 + 3] = hv.w;
      const float4 qv = *(const float4*)&Wq[(size_t)(e0 + r) * 512 + k0 + c4];
      wqs[r][c4 + 0] = qv.x; wqs[r][c4 + 1] = qv.y; wqs[r][c4 + 2] = qv.z; wqs[r][c4 + 3] = qv.w;
      const float4 kv = *(const float4*)&Wk[(size_t)(e0 + r) * 512 + k0 + c4];
      wks[r][c4 + 0] = kv.x; wks[r][c4 + 1] = kv.y; wks[r][c4 + 2] = kv.z; wks[r][c4 + 3] = kv.w;
    }
    __syncthreads();
#pragma unroll
    for (int dd = 0; dd < 16; dd++) {      // ascending within tile
      float hv[4], qv[4], kv[4];
#pragma unroll
      for (int a = 0; a < 4; a++) hv[a] = hs[ty * 4 + a][dd];
#pragma unroll
      for (int b = 0; b < 4; b++) { qv[b] = wqs[tx * 4 + b][dd]; kv[b] = wks[tx * 4 + b][dd]; }
#pragma unroll
      for (int a = 0; a < 4; a++)
#pragma unroll
        for (int b = 0; b < 4; b++) {
          aq[a][b] = fmaf(hv[a], qv[b], aq[a][b]);   // serial dep chain per output
          ak[a][b] = fmaf(hv[a], kv[b], ak[a][b]);
        }
    }
  }
#pragma unroll
  for (int a = 0; a < 4; a++)
#pragma unroll
    for (int b = 0; b < 4; b++) {
      const size_t gi = (size_t)(i0 + ty * 4 + a) * 512 + e0 + tx * 4 + b;
      Q32[gi] = aq[a][b];
      K32[gi] = ak[a][b];
      Qb[gi] = __float2bfloat16(aq[a][b]);
      Kb[gi] = __float2bfloat16(ak[a][b]);
    }
}

// ---- K2: filter logits = Qb @ Kb^T * RSQRT_D + ps*prior, diag=-inf (m97 structure) ----
__global__ __launch_bounds__(256) void k2_logits(const short* __restrict__ Qb,
                                                 const short* __restrict__ Kb,
                                                 const float* __restrict__ prior,
                                                 const float* __restrict__ psp,
                                                 float* __restrict__ out) {
  __shared__ short As[128 * 32];
  __shared__ short Bs[128 * 32];
  const int t = threadIdx.x;
  const int w = t >> 6, l = t & 63;
  const int wr = w >> 1, wc = w & 1;
  const int i0 = blockIdx.y * 128, j0 = blockIdx.x * 128;

  f32x4 acc[4][4];
#pragma unroll
  for (int a = 0; a < 4; a++)
#pragma unroll
    for (int b = 0; b < 4; b++) acc[a][b] = (f32x4){0.f, 0.f, 0.f, 0.f};

  const int rA = t >> 2;
  const int cA = (t & 3) * 8;
  const short* gA = Qb + (size_t)(i0 + rA) * 512 + cA;
  const short* gB = Kb + (size_t)(j0 + rA) * 512 + cA;
  char* lA = (char*)As + w * 1024;
  char* lB = (char*)Bs + w * 1024;

  for (int k0 = 0; k0 < 512; k0 += 32) {
    __syncthreads();
    __builtin_amdgcn_global_load_lds((__attribute__((address_space(1))) void*)(gA + k0),
                                     (__attribute__((address_space(3))) void*)(lA), 16, 0, 0);
    __builtin_amdgcn_global_load_lds((__attribute__((address_space(1))) void*)(gA + 64 * 512 + k0),
                                     (__attribute__((address_space(3))) void*)(lA + 4096), 16, 0, 0);
    __builtin_amdgcn_global_load_lds((__attribute__((address_space(1))) void*)(gB + k0),
                                     (__attribute__((address_space(3))) void*)(lB), 16, 0, 0);
    __builtin_amdgcn_global_load_lds((__attribute__((address_space(1))) void*)(gB + 64 * 512 + k0),
                                     (__attribute__((address_space(3))) void*)(lB + 4096), 16, 0, 0);
    __syncthreads();

    const int m = l & 15, kq = (l >> 4) * 8;
    short8 af[4], bfr[4];
#pragma unroll
    for (int f = 0; f < 4; f++) {
      af[f]  = *(const short8*)&As[(wr * 64 + f * 16 + m) * 32 + kq];
      bfr[f] = *(const short8*)&Bs[(wc * 64 + f * 16 + m) * 32 + kq];
    }
#pragma unroll
    for (int fr = 0; fr < 4; fr++)
#pragma unroll
      for (int fc = 0; fc < 4; fc++)
        acc[fr][fc] = __builtin_amdgcn_mfma_f32_16x16x32_bf16(af[fr], bfr[fc], acc[fr][fc], 0, 0, 0);
  }

  const float psv = psp[0];
  const int m = l & 15, q = l >> 4;
#pragma unroll
  for (int fr = 0; fr < 4; fr++) {
    const int grb = i0 + wr * 64 + fr * 16 + q * 4;
#pragma unroll
    for (int fc = 0; fc < 4; fc++) {
      const int gc = j0 + wc * 64 + fc * 16 + m;
#pragma unroll
      for (int r = 0; r < 4; r++) {
        const int gr = grb + r;
        const size_t off = (size_t)gr * 8192 + gc;
        float v = acc[fr][fc][r] * RSQRT_D + psv * prior[off];
        if (gr == gc) v = -__builtin_inff();
        out[off] = v;
      }
    }
  }
}

// ---- K3: extraction (filter, margin) + replicated-fp32 re-score + top-20 + softmax + scatter ----
__global__ __launch_bounds__(256) void k3_topk(float* out,
                                               const float* __restrict__ Q32,
                                               const float* __restrict__ K32,
                                               const float* __restrict__ prior,
                                               const float* __restrict__ psp) {
  const int row = blockIdx.x;
  const int t = threadIdx.x;
  __shared__ __align__(16) float rowv[8192];
  __shared__ __align__(16) float qrow[512];
  __shared__ unsigned long long ck[256];
  __shared__ unsigned long long wredk[4];
  __shared__ int topi[64];
  __shared__ float sel20v[20];
  __shared__ int sel20i[20];
  __shared__ double ex[20];
  __shared__ float wout[20];

  const float psv = psp[0];
  float* lrow = out + (size_t)row * 8192;
  for (int c = t; c < 2048; c += 256)
    ((float4*)rowv)[c] = ((const float4*)lrow)[c];
  for (int e = t; e < 512; e += 256)
    qrow[e] = Q32[(size_t)row * 512 + e];
  __syncthreads();

  // per-thread slice max (packed key: value desc, index asc)
  {
    unsigned long long bk = 0ull;
    for (int j = t; j < 8192; j += 256) bk = max(bk, ordkey(rowv[j], j));
    ck[t] = bk;
  }
  __syncthreads();

  int nsel = 0;
  float stopv = -__builtin_inff();
  for (int iter = 0; iter < 64; iter++) {
    unsigned long long bk = ck[t];
#pragma unroll
    for (int off = 32; off > 0; off >>= 1)
      bk = max(bk, __shfl_down(bk, off));
    if ((t & 63) == 0) wredk[t >> 6] = bk;
    __syncthreads();
    const unsigned long long mk = max(max(wredk[0], wredk[1]), max(wredk[2], wredk[3]));
    const float mv = keyval(mk);
    const int mi = keyidx(mk);
    if (nsel >= 20 && mv < stopv) break;
    if (t == 0) topi[nsel] = mi;
    nsel++;
    if (nsel == 20) stopv = mv - MARGIN;
    if (t == (mi & 255)) {
      rowv[mi] = -__builtin_inff();
      unsigned long long nk = 0ull;
      for (int j = t; j < 8192; j += 256) nk = max(nk, ordkey(rowv[j], j));
      ck[t] = nk;
    }
    __syncthreads();
  }
  __syncthreads();

  // replicated-fp32 re-score: k-sequential fmaf chain, then np's exact tail ops
  float Lf = -__builtin_inff();
  int myi = 0x7fffffff;
  if (t < 64 && t < nsel) {
    myi = topi[t];
    const float* kr = &K32[(size_t)myi * 512];
    float s = 0.f;
    for (int k = 0; k < 512; k += 4) {
      const float4 kv = *(const float4*)&kr[k];
      s = fmaf(qrow[k + 0], kv.x, s);
      s = fmaf(qrow[k + 1], kv.y, s);
      s = fmaf(qrow[k + 2], kv.z, s);
      s = fmaf(qrow[k + 3], kv.w, s);
    }
    Lf = __fdiv_rn(s, 22.62741699796952f);                        // f32(math.sqrt(512))
    Lf = __fadd_rn(Lf, __fmul_rn(psv, prior[(size_t)row * 8192 + myi]));
  }

  // wave 0: top-20 by (fp32 value DESC, index ASC) — lax.top_k semantics
  if (t < 64) {
    unsigned long long mykey = (t < nsel) ? ordkey(Lf, myi) : 0ull;
    for (int k = 0; k < 20; k++) {
      unsigned long long bk = mykey; int bs = t;
#pragma unroll
      for (int off = 1; off < 64; off <<= 1) {
        const unsigned long long k2 = __shfl_xor(bk, off);
        const int s2 = __shfl_xor(bs, off);
        if (k2 > bk) { bk = k2; bs = s2; }
      }
      if (t == 0) { sel20v[k] = keyval(bk); sel20i[k] = keyidx(bk); }
      if (t == bs) mykey = 0ull;   // keys all-distinct -> bs uniform
    }
  }
  __syncthreads();

  // softmax over the 20 kept logits (fp64 internals; diff vs fp32 ref ~1e-7 << threshold)
  if (t < 20) {
    float m = sel20v[0];
    for (int k = 1; k < 20; k++) m = fmaxf(m, sel20v[k]);
    ex[t] = exp((double)sel20v[t] - (double)m);
  }
  __syncthreads();
  if (t == 0) {
    double Z = 0.0;
    for (int k = 0; k < 20; k++) Z += ex[k];
    for (int k = 0; k < 20; k++) wout[k] = (float)(ex[k] / Z);
  }
  __syncthreads();

  const float4 z = {0.f, 0.f, 0.f, 0.f};
  for (int c = t; c < 2048; c += 256) ((float4*)lrow)[c] = z;
  __syncthreads();
  if (t < 20) lrow[sel20i[t]] = wout[t];
}

extern "C" void kernel_launch(void* const* d_in, const int* in_sizes, int n_in,
                              void* d_out, int out_size, void* d_ws, size_t ws_size,
                              hipStream_t stream) {
  const float* h     = (const float*)d_in[0];
  const float* prior = (const float*)d_in[1];
  const float* Wq    = (const float*)d_in[2];
  const float* Wk    = (const float*)d_in[3];
  const float* ps    = (const float*)d_in[4];
  float* out = (float*)d_out;

  char* ws = (char*)d_ws;
  float* Q32 = (float*)ws;                                         // 16 MB
  float* K32 = (float*)(ws + ((size_t)16 << 20));                  // 16 MB
  __hip_bfloat16* Qb = (__hip_bfloat16*)(ws + ((size_t)32 << 20)); //  8 MB
  __hip_bfloat16* Kb = (__hip_bfloat16*)(ws + ((size_t)40 << 20)); //  8 MB

  k1_qk<<<dim3(8, 128), 256, 0, stream>>>(h, Wq, Wk, Q32, K32, Qb, Kb);
  k2_logits<<<dim3(64, 64), 256, 0, stream>>>((const short*)Qb, (const short*)Kb,
                                              prior, ps, out);
  k3_topk<<<8192, 256, 0, stream>>>(out, Q32, K32, prior, ps);
}